// Round 1
// baseline (706.279 us; speedup 1.0000x reference)
//
#include <hip/hip_runtime.h>
#include <hip/hip_bf16.h>
#include <stdint.h>

#define N_NODES 10000
#define N_EDGES 320000
#define NHID    128
#define N_PAD   10112   // 79 * 128, zero-padded rows for clean 128x128 tiling

typedef unsigned short u16;
typedef float f32x4 __attribute__((ext_vector_type(4)));
typedef short bf16x8 __attribute__((ext_vector_type(8)));

// ---------------------------------------------------------------------------
// K2: edge-parallel scatter-add of raw h rows: agg[dst] += h[src]
// (aggregation commutes with the linear W: segment_sum(h@W) = segment_sum(h)@W)
// ---------------------------------------------------------------------------
__global__ __launch_bounds__(256) void scatter_kernel(
    const float* __restrict__ h,
    const int* __restrict__ esrc,
    const int* __restrict__ edst,
    float* __restrict__ agg) {
  const int total = N_EDGES * NHID;            // 40,960,000 < 2^31
  const int stride = gridDim.x * blockDim.x;
  for (int i = blockIdx.x * blockDim.x + threadIdx.x; i < total; i += stride) {
    const int e = i >> 7;
    const int c = i & (NHID - 1);
    const float v = h[(size_t)esrc[e] * NHID + c];
    atomicAdd(&agg[(size_t)edst[e] * NHID + c], v);
  }
}

// ---------------------------------------------------------------------------
// K3: x = relu(agg @ W + b); emit bf16 split x = hi + lo (two bf16 planes).
// 32 rows per 256-thread block; W staged in LDS (64 KiB), agg rows in LDS.
// Rows [N_NODES, N_PAD) are written as zeros (padding for the 128-tile GEMM).
// ---------------------------------------------------------------------------
__global__ __launch_bounds__(256) void gemm_relu_split(
    const float* __restrict__ agg,
    const float* __restrict__ W,
    const float* __restrict__ b,
    u16* __restrict__ xhi,
    u16* __restrict__ xlo) {
  __shared__ float Ws[NHID * NHID];   // 64 KiB
  __shared__ float As[32 * NHID];     // 16 KiB
  const int tid = threadIdx.x;
  const int row0 = blockIdx.x * 32;

  // stage W (coalesced float4)
  for (int i = tid; i < NHID * NHID / 4; i += 256)
    reinterpret_cast<float4*>(Ws)[i] = reinterpret_cast<const float4*>(W)[i];
  // stage 32 agg rows (guard tail: agg has only N_NODES rows)
  for (int i = tid; i < 32 * NHID / 4; i += 256) {
    const int r = row0 + (i >> 5);   // i/32 float4s per row... 128 floats = 32 float4/row
    float4 v = make_float4(0.f, 0.f, 0.f, 0.f);
    if (r < N_NODES) v = reinterpret_cast<const float4*>(agg)[(size_t)row0 * 32 + i];
    reinterpret_cast<float4*>(As)[i] = v;
  }
  __syncthreads();

  const int col = tid & (NHID - 1);
  const int half = tid >> 7;           // 0 or 1: which interleaved row set
  const float bias = b[col];

  for (int r = half; r < 32; r += 2) {
    float acc = 0.f;
#pragma unroll
    for (int k = 0; k < NHID; ++k)
      acc = fmaf(As[r * NHID + k], Ws[k * NHID + col], acc);
    const int grow = row0 + r;
    if (grow < N_PAD) {
      float x = 0.f;
      if (grow < N_NODES) x = fmaxf(acc + bias, 0.f);
      // bf16 hi/lo split via bit ops (RNE rounding)
      const uint32_t u = __builtin_bit_cast(uint32_t, x);
      const uint32_t hibits = (u + 0x7FFFu + ((u >> 16) & 1u)) & 0xFFFF0000u;
      const float hif = __builtin_bit_cast(float, hibits);
      const float lof = x - hif;
      const uint32_t ul = __builtin_bit_cast(uint32_t, lof);
      const uint32_t lobits = (ul + 0x7FFFu + ((ul >> 16) & 1u)) & 0xFFFF0000u;
      const size_t idx = (size_t)grow * NHID + col;
      xhi[idx] = (u16)(hibits >> 16);
      xlo[idx] = (u16)(lobits >> 16);
    }
  }
}

// ---------------------------------------------------------------------------
// K4: out = x @ x.T via bf16x3 MFMA (hi*hi + hi*lo + lo*hi), fp32 accumulate.
// 128x128 output tile per 256-thread block (4 waves, 2x2, 64x64 per wave).
// Fragments load directly from global (x is L2/L3 resident, ~5 MB total).
// mfma_f32_16x16x32_bf16 operand layout:
//   A: row = lane&15, k = (lane>>4)*8 + elem   (contiguous 16B per lane)
//   B: col = lane&15, k = (lane>>4)*8 + elem   (same pattern -> row of x)
//   C: col = lane&15, row = (lane>>4)*4 + reg  (m89-verified)
// ---------------------------------------------------------------------------
__global__ __launch_bounds__(256) void xxt_kernel(
    const u16* __restrict__ xhi,
    const u16* __restrict__ xlo,
    float* __restrict__ out) {
  const int bj = blockIdx.x;       // column tile
  const int bi = blockIdx.y;       // row tile
  const int lane = threadIdx.x & 63;
  const int wid = threadIdx.x >> 6;
  const int wm = (wid >> 1) * 64;
  const int wn = (wid & 1) * 64;

  const int arow = bi * 128 + wm + (lane & 15);
  const int brow = bj * 128 + wn + (lane & 15);
  const int koff = (lane >> 4) * 8;

  const u16* pah = xhi + (size_t)arow * NHID + koff;
  const u16* pal = xlo + (size_t)arow * NHID + koff;
  const u16* pbh = xhi + (size_t)brow * NHID + koff;
  const u16* pbl = xlo + (size_t)brow * NHID + koff;

  f32x4 acc[4][4];
#pragma unroll
  for (int mi = 0; mi < 4; ++mi)
#pragma unroll
    for (int ni = 0; ni < 4; ++ni)
      acc[mi][ni] = (f32x4){0.f, 0.f, 0.f, 0.f};

#pragma unroll
  for (int ks = 0; ks < 4; ++ks) {
    bf16x8 ah[4], al[4], bh[4], bl[4];
#pragma unroll
    for (int mi = 0; mi < 4; ++mi) {
      ah[mi] = *reinterpret_cast<const bf16x8*>(pah + (size_t)mi * 16 * NHID + ks * 32);
      al[mi] = *reinterpret_cast<const bf16x8*>(pal + (size_t)mi * 16 * NHID + ks * 32);
      bh[mi] = *reinterpret_cast<const bf16x8*>(pbh + (size_t)mi * 16 * NHID + ks * 32);
      bl[mi] = *reinterpret_cast<const bf16x8*>(pbl + (size_t)mi * 16 * NHID + ks * 32);
    }
#pragma unroll
    for (int mi = 0; mi < 4; ++mi)
#pragma unroll
      for (int ni = 0; ni < 4; ++ni) {
        acc[mi][ni] = __builtin_amdgcn_mfma_f32_16x16x32_bf16(ah[mi], bh[ni], acc[mi][ni], 0, 0, 0);
        acc[mi][ni] = __builtin_amdgcn_mfma_f32_16x16x32_bf16(al[mi], bh[ni], acc[mi][ni], 0, 0, 0);
        acc[mi][ni] = __builtin_amdgcn_mfma_f32_16x16x32_bf16(ah[mi], bl[ni], acc[mi][ni], 0, 0, 0);
      }
  }

  // store (row stride 40000 B is 64B-aligned -> full-line 64B segments)
  const int crow0 = bi * 128 + wm + (lane >> 4) * 4;
  const int ccol0 = bj * 128 + wn + (lane & 15);
#pragma unroll
  for (int mi = 0; mi < 4; ++mi) {
#pragma unroll
    for (int ni = 0; ni < 4; ++ni) {
      const int col = ccol0 + ni * 16;
      if (col < N_NODES) {
#pragma unroll
        for (int r = 0; r < 4; ++r) {
          const int row = crow0 + mi * 16 + r;
          if (row < N_NODES)
            out[(size_t)row * N_NODES + col] = acc[mi][ni][r];
        }
      }
    }
  }
}

// ---------------------------------------------------------------------------
extern "C" void kernel_launch(void* const* d_in, const int* in_sizes, int n_in,
                              void* d_out, int out_size, void* d_ws, size_t ws_size,
                              hipStream_t stream) {
  const float* h   = (const float*)d_in[0];
  const float* W   = (const float*)d_in[1];
  const float* b   = (const float*)d_in[2];
  const int* esrc  = (const int*)d_in[3];
  const int* edst  = (const int*)d_in[4];
  float* out = (float*)d_out;

  char* ws = (char*)d_ws;
  // workspace layout (all 16B-aligned):
  //   agg : N_NODES*NHID fp32          = 5,120,000 B
  //   xhi : N_PAD*NHID bf16            = 2,588,672 B
  //   xlo : N_PAD*NHID bf16            = 2,588,672 B
  float* agg = (float*)ws;
  u16* xhi = (u16*)(ws + 5120000);
  u16* xlo = (u16*)(ws + 5120000 + 2588672);

  hipMemsetAsync(agg, 0, (size_t)N_NODES * NHID * sizeof(float), stream);

  scatter_kernel<<<4096, 256, 0, stream>>>(h, esrc, edst, agg);

  gemm_relu_split<<<N_PAD / 32, 256, 0, stream>>>(agg, W, b, xhi, xlo);

  dim3 grid(79, 79);
  xxt_kernel<<<grid, 256, 0, stream>>>(xhi, xlo, out);
}

// Round 4
// 661.620 us; speedup vs baseline: 1.0675x; 1.0675x over previous
//
#include <hip/hip_runtime.h>
#include <hip/hip_bf16.h>
#include <stdint.h>

#define N_NODES 10000
#define N_EDGES 320000
#define NHID    128
#define N_PAD   10112   // 79 * 128, zero-padded rows for clean 128x128 tiling

typedef unsigned short u16;
typedef float f32x4 __attribute__((ext_vector_type(4)));
typedef short bf16x8 __attribute__((ext_vector_type(8)));

// ---------------------------------------------------------------------------
// CSR build stage 1: histogram of in-degrees (int atomics, 320K ops)
// ---------------------------------------------------------------------------
__global__ __launch_bounds__(256) void hist_kernel(
    const int* __restrict__ edst, int* __restrict__ cnt) {
  const int e = blockIdx.x * 256 + threadIdx.x;
  if (e < N_EDGES) atomicAdd(&cnt[edst[e]], 1);
}

// ---------------------------------------------------------------------------
// CSR build stage 2: exclusive prefix sum over 10000 counts (1 block).
// ---------------------------------------------------------------------------
__global__ __launch_bounds__(1024) void scan_kernel(
    const int* __restrict__ cnt, int* __restrict__ offs) {
  __shared__ int wsum[16];
  __shared__ int carry_s;
  const int tid = threadIdx.x;
  const int lane = tid & 63;
  const int wv = tid >> 6;
  if (tid == 0) carry_s = 0;
  __syncthreads();
  for (int base = 0; base < N_NODES; base += 1024) {
    const int i = base + tid;
    const int v = (i < N_NODES) ? cnt[i] : 0;
    int s = v;
#pragma unroll
    for (int d = 1; d < 64; d <<= 1) {
      int t = __shfl_up(s, d);
      if (lane >= d) s += t;
    }
    if (lane == 63) wsum[wv] = s;
    __syncthreads();
    if (tid < 16) {
      int t = wsum[tid];
#pragma unroll
      for (int d = 1; d < 16; d <<= 1) {
        int u = __shfl_up(t, d);
        if (tid >= d) t += u;
      }
      wsum[tid] = t;   // inclusive scan of wave totals
    }
    __syncthreads();
    const int carry = carry_s;
    const int pre = (wv == 0 ? 0 : wsum[wv - 1]);
    if (i < N_NODES) offs[i] = carry + pre + (s - v);
    __syncthreads();
    if (tid == 0) carry_s = carry + wsum[15];
    __syncthreads();
  }
  if (tid == 0) offs[N_NODES] = N_EDGES;
}

// ---------------------------------------------------------------------------
// CSR build stage 3: bucket-fill sorted src list (int atomics on cursors)
// ---------------------------------------------------------------------------
__global__ __launch_bounds__(256) void fill_kernel(
    const int* __restrict__ esrc, const int* __restrict__ edst,
    const int* __restrict__ offs, int* __restrict__ cursor,
    int* __restrict__ srcs) {
  const int e = blockIdx.x * 256 + threadIdx.x;
  if (e < N_EDGES) {
    const int d = edst[e];
    const int p = atomicAdd(&cursor[d], 1);
    srcs[offs[d] + p] = esrc[e];
  }
}

// ---------------------------------------------------------------------------
// Gather: agg[n] = sum over in-edges of h[src].  One block per node, thread =
// column. Plain coalesced loads (h is L2/L3 resident), zero float atomics.
// ---------------------------------------------------------------------------
__global__ __launch_bounds__(128) void gather_kernel(
    const float* __restrict__ h,
    const int* __restrict__ offs,
    const int* __restrict__ srcs,
    float* __restrict__ agg) {
  __shared__ int sl[256];
  const int n = blockIdx.x;
  const int c = threadIdx.x;
  const int beg = offs[n];
  const int deg = offs[n + 1] - beg;
  float acc = 0.f;
  for (int j0 = 0; j0 < deg; j0 += 256) {
    const int m = min(deg - j0, 256);
    for (int j = c; j < m; j += 128) sl[j] = srcs[beg + j0 + j];
    __syncthreads();
#pragma unroll 4
    for (int j = 0; j < m; ++j)
      acc += h[(size_t)sl[j] * NHID + c];
    __syncthreads();
  }
  agg[(size_t)n * NHID + c] = acc;
}

// ---------------------------------------------------------------------------
// x = relu(agg @ W + b); emit bf16 split x = hi + lo (two bf16 planes).
// ---------------------------------------------------------------------------
__global__ __launch_bounds__(256) void gemm_relu_split(
    const float* __restrict__ agg,
    const float* __restrict__ W,
    const float* __restrict__ b,
    u16* __restrict__ xhi,
    u16* __restrict__ xlo) {
  __shared__ float Ws[NHID * NHID];   // 64 KiB
  __shared__ float As[32 * NHID];     // 16 KiB
  const int tid = threadIdx.x;
  const int row0 = blockIdx.x * 32;

  for (int i = tid; i < NHID * NHID / 4; i += 256)
    reinterpret_cast<float4*>(Ws)[i] = reinterpret_cast<const float4*>(W)[i];
  for (int i = tid; i < 32 * NHID / 4; i += 256) {
    const int r = row0 + (i >> 5);
    float4 v = make_float4(0.f, 0.f, 0.f, 0.f);
    if (r < N_NODES) v = reinterpret_cast<const float4*>(agg)[(size_t)row0 * 32 + i];
    reinterpret_cast<float4*>(As)[i] = v;
  }
  __syncthreads();

  const int col = tid & (NHID - 1);
  const int half = tid >> 7;
  const float bias = b[col];

  for (int r = half; r < 32; r += 2) {
    float acc = 0.f;
#pragma unroll
    for (int k = 0; k < NHID; ++k)
      acc = fmaf(As[r * NHID + k], Ws[k * NHID + col], acc);
    const int grow = row0 + r;
    float x = 0.f;
    if (grow < N_NODES) x = fmaxf(acc + bias, 0.f);
    const uint32_t u = __builtin_bit_cast(uint32_t, x);
    const uint32_t hibits = (u + 0x7FFFu + ((u >> 16) & 1u)) & 0xFFFF0000u;
    const float hif = __builtin_bit_cast(float, hibits);
    const float lof = x - hif;
    const uint32_t ul = __builtin_bit_cast(uint32_t, lof);
    const uint32_t lobits = (ul + 0x7FFFu + ((ul >> 16) & 1u)) & 0xFFFF0000u;
    const size_t idx = (size_t)grow * NHID + col;
    xhi[idx] = (u16)(hibits >> 16);
    xlo[idx] = (u16)(lobits >> 16);
  }
}

// ---------------------------------------------------------------------------
// out = x @ x.T via bf16x3 MFMA (hi*hi + hi*lo + lo*hi), fp32 accumulate.
// 128x128 tile per block, bijective XCD-aware swizzle for A-panel L2 reuse.
// ---------------------------------------------------------------------------
__global__ __launch_bounds__(256) void xxt_kernel(
    const u16* __restrict__ xhi,
    const u16* __restrict__ xlo,
    float* __restrict__ out) {
  const int nwg = 79 * 79;               // 6241
  const int flat = blockIdx.y * 79 + blockIdx.x;
  const int q = nwg >> 3, r = nwg & 7;   // 780, 1
  const int xcd = flat & 7;
  const int jj = flat >> 3;
  const int nid = (xcd < r ? xcd * (q + 1) : r * (q + 1) + (xcd - r) * q) + jj;
  const int bi = nid / 79;
  const int bj = nid % 79;

  const int lane = threadIdx.x & 63;
  const int wid = threadIdx.x >> 6;
  const int wm = (wid >> 1) * 64;
  const int wn = (wid & 1) * 64;

  const int arow = bi * 128 + wm + (lane & 15);
  const int brow = bj * 128 + wn + (lane & 15);
  const int koff = (lane >> 4) * 8;

  const u16* pah = xhi + (size_t)arow * NHID + koff;
  const u16* pal = xlo + (size_t)arow * NHID + koff;
  const u16* pbh = xhi + (size_t)brow * NHID + koff;
  const u16* pbl = xlo + (size_t)brow * NHID + koff;

  f32x4 acc[4][4];
#pragma unroll
  for (int mi = 0; mi < 4; ++mi)
#pragma unroll
    for (int ni = 0; ni < 4; ++ni)
      acc[mi][ni] = (f32x4){0.f, 0.f, 0.f, 0.f};

#pragma unroll
  for (int ks = 0; ks < 4; ++ks) {
    bf16x8 ah[4], al[4], bh[4], bl[4];
#pragma unroll
    for (int mi = 0; mi < 4; ++mi) {
      ah[mi] = *reinterpret_cast<const bf16x8*>(pah + (size_t)mi * 16 * NHID + ks * 32);
      al[mi] = *reinterpret_cast<const bf16x8*>(pal + (size_t)mi * 16 * NHID + ks * 32);
      bh[mi] = *reinterpret_cast<const bf16x8*>(pbh + (size_t)mi * 16 * NHID + ks * 32);
      bl[mi] = *reinterpret_cast<const bf16x8*>(pbl + (size_t)mi * 16 * NHID + ks * 32);
    }
#pragma unroll
    for (int mi = 0; mi < 4; ++mi)
#pragma unroll
      for (int ni = 0; ni < 4; ++ni) {
        acc[mi][ni] = __builtin_amdgcn_mfma_f32_16x16x32_bf16(ah[mi], bh[ni], acc[mi][ni], 0, 0, 0);
        acc[mi][ni] = __builtin_amdgcn_mfma_f32_16x16x32_bf16(al[mi], bh[ni], acc[mi][ni], 0, 0, 0);
        acc[mi][ni] = __builtin_amdgcn_mfma_f32_16x16x32_bf16(ah[mi], bl[ni], acc[mi][ni], 0, 0, 0);
      }
  }

  const int crow0 = bi * 128 + wm + (lane >> 4) * 4;
  const int ccol0 = bj * 128 + wn + (lane & 15);
#pragma unroll
  for (int mi = 0; mi < 4; ++mi) {
#pragma unroll
    for (int ni = 0; ni < 4; ++ni) {
      const int col = ccol0 + ni * 16;
      if (col < N_NODES) {
#pragma unroll
        for (int r = 0; r < 4; ++r) {
          const int row = crow0 + mi * 16 + r;
          if (row < N_NODES)
            out[(size_t)row * N_NODES + col] = acc[mi][ni][r];
        }
      }
    }
  }
}

// ---------------------------------------------------------------------------
extern "C" void kernel_launch(void* const* d_in, const int* in_sizes, int n_in,
                              void* d_out, int out_size, void* d_ws, size_t ws_size,
                              hipStream_t stream) {
  const float* h   = (const float*)d_in[0];
  const float* W   = (const float*)d_in[1];
  const float* b   = (const float*)d_in[2];
  const int* esrc  = (const int*)d_in[3];
  const int* edst  = (const int*)d_in[4];
  float* out = (float*)d_out;

  char* ws = (char*)d_ws;
  // workspace layout (16B aligned):
  float* agg  = (float*)(ws);                    // 5,120,000 B
  u16* xhi    = (u16*)(ws + 5120000);            // 2,588,672 B
  u16* xlo    = (u16*)(ws + 7708672);            // 2,588,672 B
  int* cnt    = (int*)(ws + 10297344);           //    40,000 B
  int* cursor = (int*)(ws + 10337344);           //    40,000 B (contiguous w/ cnt)
  int* offs   = (int*)(ws + 10377344);           //    40,016 B
  int* srcs   = (int*)(ws + 10417360);           // 1,280,000 B

  // zero cnt + cursor in one shot (contiguous)
  hipMemsetAsync(cnt, 0, 80000, stream);

  hist_kernel<<<(N_EDGES + 255) / 256, 256, 0, stream>>>(edst, cnt);
  scan_kernel<<<1, 1024, 0, stream>>>(cnt, offs);
  fill_kernel<<<(N_EDGES + 255) / 256, 256, 0, stream>>>(esrc, edst, offs, cursor, srcs);
  gather_kernel<<<N_NODES, 128, 0, stream>>>(h, offs, srcs, agg);

  gemm_relu_split<<<N_PAD / 32, 256, 0, stream>>>(agg, W, b, xhi, xlo);

  dim3 grid(79, 79);
  xxt_kernel<<<grid, 256, 0, stream>>>(xhi, xlo, out);
}